// Round 1
// baseline (75432.239 us; speedup 1.0000x reference)
//
#include <hip/hip_runtime.h>
#include <math.h>

// Bilinear weights exactly mirroring the reference resize_bilinear:
// ratio computed in double then cast to f32 (JAX weak-type promotion),
// coords in f32, clip, floor, neighbor clamp.
__device__ __forceinline__ void bl_w(int o, int O, int I, int& i0, int& i1, float& w) {
    float r = (float)((double)I / (double)O);
    float f = (o + 0.5f) * r - 0.5f;
    f = fminf(fmaxf(f, 0.0f), (float)(I - 1));
    int a = (int)floorf(f);
    i0 = a;
    i1 = min(a + 1, I - 1);
    w = f - (float)a;
}

// Meta: per (b,lvl): crop rects (exact int math), mh/mw, 3 filter sizes.
// Layout per (b,lvl), stride ms: [0]=mh [1]=mw ; [2+4n..] = t,l,ch,cw ;
// [2+4N + 2s..] = fh,fw for s in {1.0, 0.9, 1.1}
__global__ void k_meta(const int* __restrict__ tlbr, const int* __restrict__ p_imgh,
                       const int* __restrict__ p_imgw, int B, int N, int ms,
                       int* __restrict__ meta) {
    if (blockIdx.x != 0 || threadIdx.x != 0) return;
    const int HFs[2] = {128, 64};
    const double SC[2] = {0.9, 1.1};
    int img_h = *p_imgh, img_w = *p_imgw;
    for (int b = 0; b < B; ++b)
      for (int lvl = 0; lvl < 2; ++lvl) {
        int HF = HFs[lvl], WF = HFs[lvl];
        double sh = (double)HF / (double)img_h;
        double sw = (double)WF / (double)img_w;
        int* m = meta + (b*2 + lvl)*ms;
        int mh = 0, mw = 0;
        for (int n = 0; n < N; ++n) {
            const int* bx = tlbr + ((size_t)(b*N) + n)*4;
            int t  = max((int)floor((double)bx[0]*sh), 0);
            int l  = max((int)floor((double)bx[1]*sw), 0);
            int bb = min((int)ceil((double)bx[2]*sh) + 1, HF);
            int rr = min((int)ceil((double)bx[3]*sw) + 1, WF);
            int chh = bb - t, cww = rr - l;
            m[2+4*n+0] = t; m[2+4*n+1] = l; m[2+4*n+2] = chh; m[2+4*n+3] = cww;
            mh = max(mh, chh); mw = max(mw, cww);
        }
        m[0] = mh; m[1] = mw;
        int fo = 2 + 4*N;
        m[fo+0] = mh; m[fo+1] = mw;   // scale 1.0
        for (int s = 0; s < 2; ++s) {
            int hs  = (int)ceil((double)mh * SC[s]); if (hs  <= 1) hs  = mh;
            int wsv = (int)ceil((double)mw * SC[s]); if (wsv <= 1) wsv = mw;
            m[fo+2+2*s] = hs; m[fo+2+2*s+1] = wsv;
        }
      }
}

// Crop -> (mh,mw) bilinear patches. One thread per patch element (padded grid).
__global__ void k_patches(const float* __restrict__ feat_all, int C, int HF, int WF,
                          float* __restrict__ patches, int MH, int MW,
                          int B, int N, int lvl, int ms, const int* __restrict__ meta) {
    long long idx = (long long)blockIdx.x * blockDim.x + threadIdx.x;
    long long total = (long long)B * N * C * MH * MW;
    if (idx >= total) return;
    int px = (int)(idx % MW); long long r = idx / MW;
    int py = (int)(r % MH); r /= MH;
    int c  = (int)(r % C);  r /= C;
    int n  = (int)(r % N);
    int b  = (int)(r / N);
    const int* m = meta + (b*2 + lvl)*ms;
    int mh = m[0], mw = m[1];
    if (py >= mh || px >= mw) return;
    int t = m[2+4*n], l = m[3+4*n], chh = m[4+4*n], cww = m[5+4*n];
    int y0, y1, x0, x1; float wy, wx;
    bl_w(py, mh, chh, y0, y1, wy);
    bl_w(px, mw, cww, x0, x1, wx);
    const float* src = feat_all + ((size_t)b * C + c) * HF * WF;
    float f00 = src[(t + y0) * WF + (l + x0)];
    float f10 = src[(t + y1) * WF + (l + x0)];
    float f01 = src[(t + y0) * WF + (l + x1)];
    float f11 = src[(t + y1) * WF + (l + x1)];
    float v = (f00 * (1.f - wy) + f10 * wy) * (1.f - wx)
            + (f01 * (1.f - wy) + f11 * wy) * wx;
    patches[(((size_t)(b*N + n) * C + c) * MH + py) * MW + px] = v;
}

// Direct xcorr, filter chunk (CC channels) resized on the fly into LDS.
// grid: (WF/16, HF/16, B*3*N), block 256 = 16x16 output tile.
template<int CC, int LDSFLOATS>
__global__ void k_conv(const float* __restrict__ feat_all, int C, int HF, int WF,
                       const float* __restrict__ patches, int MH, int MW,
                       int B, int N, int lvl, int ms, const int* __restrict__ meta,
                       float* __restrict__ out, int direct) {
    __shared__ float lds[LDSFLOATS];
    int bz = blockIdx.z;
    int n  = bz % N; int t2 = bz / N;
    int sc = t2 % 3; int b  = t2 / 3;
    const int* m = meta + (b*2 + lvl)*ms;
    int mh = m[0], mw = m[1];
    int fo = 2 + 4*N;
    int fh = m[fo + 2*sc], fwd = m[fo + 2*sc + 1];
    int pad_t = fh / 2, pad_l = fwd / 2;
    int tx = threadIdx.x % 16, ty = threadIdx.x / 16;
    int x = blockIdx.x * 16 + tx, y = blockIdx.y * 16 + ty;
    const float* feat = feat_all + (size_t)b * C * HF * WF;
    const float* pat  = patches + (size_t)(b*N + n) * C * MH * MW;
    int farea = fh * fwd;
    float acc = 0.f;
    for (int c0 = 0; c0 < C; c0 += CC) {
        for (int e = threadIdx.x; e < CC * farea; e += 256) {
            int cc = e / farea; int rr = e - cc * farea;
            int fy = rr / fwd, fx = rr - fy * fwd;
            int y0, y1, x0, x1; float wy, wx;
            bl_w(fy, fh, mh, y0, y1, wy);
            bl_w(fx, fwd, mw, x0, x1, wx);
            const float* ps = pat + (size_t)(c0 + cc) * MH * MW;
            float f00 = ps[y0*MW + x0], f10 = ps[y1*MW + x0];
            float f01 = ps[y0*MW + x1], f11 = ps[y1*MW + x1];
            lds[e] = (f00 * (1.f - wy) + f10 * wy) * (1.f - wx)
                   + (f01 * (1.f - wy) + f11 * wy) * wx;
        }
        __syncthreads();
        for (int cc = 0; cc < CC; ++cc) {
            const float* fsrc = feat + (size_t)(c0 + cc) * HF * WF;
            const float* flds = lds + cc * farea;
            for (int fy = 0; fy < fh; ++fy) {
                int iy = y - pad_t + fy;
                if (iy < 0 || iy >= HF) continue;
                const float* frow = fsrc + (size_t)iy * WF;
                const float* wrow = flds + fy * fwd;
                for (int fx = 0; fx < fwd; ++fx) {
                    int ix = x - pad_l + fx;
                    float fv = (ix >= 0 && ix < WF) ? frow[ix] : 0.f;
                    acc += fv * wrow[fx];
                }
            }
        }
        __syncthreads();
    }
    size_t oi;
    if (direct) oi = ((size_t)((b*N + n) * 6 + sc) * HF + y) * WF + x;       // m3 sims: already 128x128
    else        oi = ((size_t)((b*N + n) * 3 + sc) * HF + y) * WF + x;       // m4 sims -> ws buffer
    out[oi] = acc;
}

// 64x64 -> 128x128 bilinear upsample of m4 sims into out slots s=3..5.
__global__ void k_upsample(const float* __restrict__ sim4, float* __restrict__ out,
                           int B, int N) {
    int idx = blockIdx.x * blockDim.x + threadIdx.x;
    int total = B * N * 3 * 128 * 128;
    if (idx >= total) return;
    int x = idx % 128; int r = idx / 128;
    int y = r % 128; r /= 128;
    int sc = r % 3; r /= 3;
    int n = r % N; int b = r / N;
    int y0, y1, x0, x1; float wy, wx;
    bl_w(y, 128, 64, y0, y1, wy);
    bl_w(x, 128, 64, x0, x1, wx);
    const float* s = sim4 + (size_t)((b*N + n) * 3 + sc) * 64 * 64;
    float f00 = s[y0*64 + x0], f10 = s[y1*64 + x0];
    float f01 = s[y0*64 + x1], f11 = s[y1*64 + x1];
    out[((size_t)((b*N + n) * 6 + 3 + sc) * 128 + y) * 128 + x] =
        (f00 * (1.f - wy) + f10 * wy) * (1.f - wx)
      + (f01 * (1.f - wy) + f11 * wy) * wx;
}

extern "C" void kernel_launch(void* const* d_in, const int* in_sizes, int n_in,
                              void* d_out, int out_size, void* d_ws, size_t ws_size,
                              hipStream_t stream) {
    const float* map3 = (const float*)d_in[0];
    const float* map4 = (const float*)d_in[1];
    const int*   tlbr = (const int*)d_in[2];
    const int*   p_imgh = (const int*)d_in[3];
    const int*   p_imgw = (const int*)d_in[4];
    float* out = (float*)d_out;

    const int C3 = 512, H3 = 128, C4 = 1024, H4 = 64;
    int B = in_sizes[0] / (C3 * H3 * H3);
    int N = in_sizes[2] / (B * 4);
    int ms = 2 + 4 * N + 6;

    // Workspace: meta (4KB) | sim4 buffer | shared patch buffer (reused per level)
    const int MH3 = 24, MW3 = 24, MH4 = 16, MW4 = 16;  // >= actual mh/mw for these inputs
    int* meta = (int*)d_ws;
    float* sim4 = (float*)((char*)d_ws + 4096);
    size_t sim4_elems = (size_t)B * N * 3 * H4 * H4;
    float* patch_buf = sim4 + sim4_elems;

    k_meta<<<1, 1, 0, stream>>>(tlbr, p_imgh, p_imgw, B, N, ms, meta);

    // ---- level 0 (m3): patches -> conv direct to out ----
    {
        long long tot = (long long)B * N * C3 * MH3 * MW3;
        int blocks = (int)((tot + 255) / 256);
        k_patches<<<blocks, 256, 0, stream>>>(map3, C3, H3, H3, patch_buf, MH3, MW3,
                                              B, N, 0, ms, meta);
        dim3 g0(H3 / 16, H3 / 16, B * 3 * N);
        k_conv<8, 8*27*27><<<g0, 256, 0, stream>>>(map3, C3, H3, H3, patch_buf, MH3, MW3,
                                                   B, N, 0, ms, meta, out, 1);
    }
    // ---- level 1 (m4): patches (reuse buffer) -> conv to sim4 -> upsample ----
    {
        long long tot = (long long)B * N * C4 * MH4 * MW4;
        int blocks = (int)((tot + 255) / 256);
        k_patches<<<blocks, 256, 0, stream>>>(map4, C4, H4, H4, patch_buf, MH4, MW4,
                                              B, N, 1, ms, meta);
        dim3 g1(H4 / 16, H4 / 16, B * 3 * N);
        k_conv<8, 8*16*16><<<g1, 256, 0, stream>>>(map4, C4, H4, H4, patch_buf, MH4, MW4,
                                                   B, N, 1, ms, meta, sim4, 0);
        int tot2 = B * N * 3 * H3 * H3;
        k_upsample<<<(tot2 + 255) / 256, 256, 0, stream>>>(sim4, out, B, N);
    }
}

// Round 2
// 2963.408 us; speedup vs baseline: 25.4546x; 25.4546x over previous
//
#include <hip/hip_runtime.h>
#include <math.h>

typedef float  fx4  __attribute__((ext_vector_type(4)));
typedef short  bfx8 __attribute__((ext_vector_type(8)));

// Bilinear weights exactly mirroring the reference resize_bilinear.
__device__ __forceinline__ void bl_w(int o, int O, int I, int& i0, int& i1, float& w) {
    float r = (float)((double)I / (double)O);
    float f = (o + 0.5f) * r - 0.5f;
    f = fminf(fmaxf(f, 0.0f), (float)(I - 1));
    int a = (int)floorf(f);
    i0 = a;
    i1 = min(a + 1, I - 1);
    w = f - (float)a;
}

__device__ __forceinline__ unsigned int bf16rne(float f) {
    unsigned int x = __builtin_bit_cast(unsigned int, f);
    return ((x + 0x7fffu + ((x >> 16) & 1u)) >> 16) & 0xffffu;
}

// Meta: per (b,lvl): [0]=mh [1]=mw ; [2+4n..]=t,l,ch,cw ; [2+4N+2s..]=fh,fw (s=1.0,0.9,1.1)
__global__ void k_meta(const int* __restrict__ tlbr, const int* __restrict__ p_imgh,
                       const int* __restrict__ p_imgw, int B, int N, int ms,
                       int* __restrict__ meta) {
    if (blockIdx.x != 0 || threadIdx.x != 0) return;
    const int HFs[2] = {128, 64};
    const double SC[2] = {0.9, 1.1};
    int img_h = *p_imgh, img_w = *p_imgw;
    for (int b = 0; b < B; ++b)
      for (int lvl = 0; lvl < 2; ++lvl) {
        int HF = HFs[lvl], WF = HFs[lvl];
        double sh = (double)HF / (double)img_h;
        double sw = (double)WF / (double)img_w;
        int* m = meta + (b*2 + lvl)*ms;
        int mh = 0, mw = 0;
        for (int n = 0; n < N; ++n) {
            const int* bx = tlbr + ((size_t)(b*N) + n)*4;
            int t  = max((int)floor((double)bx[0]*sh), 0);
            int l  = max((int)floor((double)bx[1]*sw), 0);
            int bb = min((int)ceil((double)bx[2]*sh) + 1, HF);
            int rr = min((int)ceil((double)bx[3]*sw) + 1, WF);
            int chh = bb - t, cww = rr - l;
            m[2+4*n+0] = t; m[2+4*n+1] = l; m[2+4*n+2] = chh; m[2+4*n+3] = cww;
            mh = max(mh, chh); mw = max(mw, cww);
        }
        m[0] = mh; m[1] = mw;
        int fo = 2 + 4*N;
        m[fo+0] = mh; m[fo+1] = mw;
        for (int s = 0; s < 2; ++s) {
            int hs  = (int)ceil((double)mh * SC[s]); if (hs  <= 1) hs  = mh;
            int wsv = (int)ceil((double)mw * SC[s]); if (wsv <= 1) wsv = mw;
            m[fo+2+2*s] = hs; m[fo+2+2*s+1] = wsv;
        }
      }
}

// Crop -> (mh,mw) fp32 patches.
__global__ void k_patches(const float* __restrict__ feat_all, int C, int HF, int WF,
                          float* __restrict__ patches, int MH, int MW,
                          int B, int N, int lvl, int ms, const int* __restrict__ meta) {
    long long idx = (long long)blockIdx.x * blockDim.x + threadIdx.x;
    long long total = (long long)B * N * C * MH * MW;
    if (idx >= total) return;
    int px = (int)(idx % MW); long long r = idx / MW;
    int py = (int)(r % MH); r /= MH;
    int c  = (int)(r % C);  r /= C;
    int n  = (int)(r % N);
    int b  = (int)(r / N);
    const int* m = meta + (b*2 + lvl)*ms;
    int mh = m[0], mw = m[1];
    if (py >= mh || px >= mw) return;
    int t = m[2+4*n], l = m[3+4*n], chh = m[4+4*n], cww = m[5+4*n];
    int y0, y1, x0, x1; float wy, wx;
    bl_w(py, mh, chh, y0, y1, wy);
    bl_w(px, mw, cww, x0, x1, wx);
    const float* src = feat_all + ((size_t)b * C + c) * HF * WF;
    float f00 = src[(t + y0) * WF + (l + x0)];
    float f10 = src[(t + y1) * WF + (l + x0)];
    float f01 = src[(t + y0) * WF + (l + x1)];
    float f11 = src[(t + y1) * WF + (l + x1)];
    float v = (f00 * (1.f - wy) + f10 * wy) * (1.f - wx)
            + (f01 * (1.f - wy) + f11 * wy) * wx;
    patches[(((size_t)(b*N + n) * C + c) * MH + py) * MW + px] = v;
}

// Build bf16 filters, zero-embedded in KHxKW canvas, directly in MFMA A-frag
// swizzled order: u32 pair index = (((lb*KT + kt)*4 + g)*16 + m)*4 + jj/2,
// where k = kt*32 + g*8 + jj, k = c*KH*KW + kx*KH + ky (ky innermost!).
template<int C, int KH, int KW, int MH, int MW>
__global__ void k_filters(const float* __restrict__ patches, const int* __restrict__ meta,
                          unsigned short* __restrict__ Wswz, int b0, int chunkB,
                          int N, int lvl, int ms) {
    constexpr int KHW = KH*KW;
    constexpr int KT  = C*KHW/32;
    long long idx = (long long)blockIdx.x*256 + threadIdx.x;
    long long total = (long long)chunkB * KT * 256;   // u32 pairs
    if (idx >= total) return;
    int jj = ((int)(idx & 3)) * 2;
    int m  = (int)((idx >> 2) & 15);
    int g  = (int)((idx >> 6) & 3);
    long long rest = idx >> 8;
    int kt = (int)(rest % KT);
    int lb = (int)(rest / KT);
    unsigned int outv = 0;
    int sc = m / N, n = m - sc*N;
    if (sc < 3) {
        int b = b0 + lb;
        const int* mt = meta + (b*2 + lvl)*ms;
        int mh = mt[0], mw = mt[1];
        int fo = 2 + 4*N;
        int fh = mt[fo + 2*sc], fw = mt[fo + 2*sc + 1];
        int offy = KH/2 - fh/2, offx = KW/2 - fw/2;
        int k = kt*32 + g*8 + jj;
        int c = k / KHW; int rem = k - c*KHW;
        int kx = rem / KH; int ky = rem - kx*KH;
        int fx = kx - offx;
        if (fx >= 0 && fx < fw) {
            const float* pat = patches + ((size_t)(b*N + n)*C + c)*(MH*MW);
            int x0,x1,y0,y1; float wx,wy;
            bl_w(fx, fw, mw, x0, x1, wx);
            #pragma unroll
            for (int q = 0; q < 2; ++q) {
                int fy = ky + q - offy;
                if (fy >= 0 && fy < fh) {
                    bl_w(fy, fh, mh, y0, y1, wy);
                    float v = (pat[y0*MW+x0]*(1.f-wy) + pat[y1*MW+x0]*wy)*(1.f-wx)
                            + (pat[y0*MW+x1]*(1.f-wy) + pat[y1*MW+x1]*wy)*wx;
                    outv |= bf16rne(v) << (16*q);
                }
            }
        }
    }
    ((unsigned int*)Wswz)[idx] = outv;
}

// MFMA implicit-GEMM xcorr. Block = one output row (W pixels), 4 waves,
// NT N-tiles of 16 pixels per wave. Feature tile staged column-major bf16 in
// LDS (cols = x_out+kx, rows = ky), so B-frag = one aligned ds_read_b128.
template<int C, int KH, int KW, int H, int W, int CC, int NT, int NCOLP, int RSTR, int P>
__global__ __launch_bounds__(256, 2) void k_mfconv(
        const float* __restrict__ feat_all, const unsigned short* __restrict__ Wswz,
        float* __restrict__ dst, int b0, int N, int planes) {
    constexpr int KHW    = KH*KW;
    constexpr int KSC    = KHW/32;          // K-steps per channel
    constexpr int NKK    = CC*KSC;          // K-steps per staged chunk
    constexpr int CHSTRB = NCOLP*RSTR*2;    // LDS bytes per channel
    constexpr int NCT    = NCOLP/4;
    constexpr int NROWT  = KH/4;
    constexpr int KT     = C*KSC;
    __shared__ __align__(16) unsigned char smem[CC*CHSTRB + NKK*16];
    unsigned int* tbl = (unsigned int*)(smem + CC*CHSTRB);

    const int y0  = blockIdx.x;
    const int lb  = blockIdx.y;
    const int b   = b0 + lb;
    const int tid = threadIdx.x;
    const int lane = tid & 63;
    const int wv   = tid >> 6;
    const int g    = lane >> 4;
    const int lm   = lane & 15;

    for (int e = tid; e < NKK*4; e += 256) {
        int kk = e >> 2, gg = e & 3;
        int kb = kk*32 + gg*8;
        int cof = kb / KHW; int rem = kb - cof*KHW;
        int kx = rem / KH;  int ky = rem - kx*KH;
        tbl[e] = (unsigned int)(cof*CHSTRB + (kx*RSTR + ky)*2);
    }

    fx4 acc[NT];
    #pragma unroll
    for (int t = 0; t < NT; ++t) acc[t] = (fx4){0.f, 0.f, 0.f, 0.f};
    int xoff[NT];
    #pragma unroll
    for (int t = 0; t < NT; ++t) xoff[t] = ((wv*NT + t)*16 + lm) * (RSTR*2);

    const float* feat = feat_all + (size_t)b * C * H * W;
    const unsigned short* Wb = Wswz + ((size_t)lb*KT)*512 + lane*8;

    for (int c0 = 0; c0 < C; c0 += CC) {
        // ---- stage CC channels, column-major bf16, 4x4 transpose blocks ----
        for (int it = tid; it < CC*NROWT*NCT; it += 256) {
            int ct = it % NCT; int t2 = it / NCT;
            int rt = t2 % NROWT; int ch = t2 / NROWT;
            const float* src = feat + (size_t)(c0 + ch)*H*W;
            int col0 = ct*4, r0 = rt*4;
            int x0 = col0 - P;
            float v[4][4];
            #pragma unroll
            for (int rr = 0; rr < 4; ++rr) {
                int y = y0 + r0 + rr - P;
                bool yok = (y >= 0) && (y < H);
                if (yok && x0 >= 0 && x0 + 3 < W) {
                    const float4 f = *reinterpret_cast<const float4*>(src + (size_t)y*W + x0);
                    v[rr][0] = f.x; v[rr][1] = f.y; v[rr][2] = f.z; v[rr][3] = f.w;
                } else {
                    #pragma unroll
                    for (int j = 0; j < 4; ++j) {
                        int x = x0 + j;
                        v[rr][j] = (yok && x >= 0 && x < W) ? src[(size_t)y*W + x] : 0.f;
                    }
                }
            }
            #pragma unroll
            for (int j = 0; j < 4; ++j) {
                unsigned int lo = bf16rne(v[0][j]) | (bf16rne(v[1][j]) << 16);
                unsigned int hi = bf16rne(v[2][j]) | (bf16rne(v[3][j]) << 16);
                *reinterpret_cast<uint2*>(smem + ch*CHSTRB + ((col0 + j)*RSTR + r0)*2)
                    = make_uint2(lo, hi);
            }
        }
        __syncthreads();
        // ---- MFMA K-loop over this chunk ----
        const unsigned short* Wk = Wb + (size_t)(c0*KSC)*512;
        #pragma unroll 4
        for (int kk = 0; kk < NKK; ++kk) {
            unsigned int tb = tbl[kk*4 + g];
            bfx8 af = *reinterpret_cast<const bfx8*>(Wk + (size_t)kk*512);
            #pragma unroll
            for (int t = 0; t < NT; ++t) {
                bfx8 bq = *reinterpret_cast<const bfx8*>(smem + tb + xoff[t]);
                acc[t] = __builtin_amdgcn_mfma_f32_16x16x32_bf16(af, bq, acc[t], 0, 0, 0);
            }
        }
        __syncthreads();
    }
    // ---- epilogue: D row=(lane>>4)*4+r = filter m (sc*N+n), col=lane&15 ----
    #pragma unroll
    for (int t = 0; t < NT; ++t) {
        int x = (wv*NT + t)*16 + lm;
        #pragma unroll
        for (int r = 0; r < 4; ++r) {
            int m  = g*4 + r;
            int sc = m / N;
            int n  = m - sc*N;
            if (sc < 3) {
                size_t oi = ((size_t)((b*N + n)*planes + sc)*H + y0)*W + x;
                dst[oi] = acc[t][r];
            }
        }
    }
}

// 64x64 -> 128x128 bilinear upsample of m4 sims into out slots s=3..5.
__global__ void k_upsample(const float* __restrict__ sim4, float* __restrict__ out,
                           int B, int N) {
    int idx = blockIdx.x * blockDim.x + threadIdx.x;
    int total = B * N * 3 * 128 * 128;
    if (idx >= total) return;
    int x = idx % 128; int r = idx / 128;
    int y = r % 128; r /= 128;
    int sc = r % 3; r /= 3;
    int n = r % N; int b = r / N;
    int y0, y1, x0, x1; float wy, wx;
    bl_w(y, 128, 64, y0, y1, wy);
    bl_w(x, 128, 64, x0, x1, wx);
    const float* s = sim4 + (size_t)((b*N + n) * 3 + sc) * 64 * 64;
    float f00 = s[y0*64 + x0], f10 = s[y1*64 + x0];
    float f01 = s[y0*64 + x1], f11 = s[y1*64 + x1];
    out[((size_t)((b*N + n) * 6 + 3 + sc) * 128 + y) * 128 + x] =
        (f00 * (1.f - wy) + f10 * wy) * (1.f - wx)
      + (f01 * (1.f - wy) + f11 * wy) * wx;
}

extern "C" void kernel_launch(void* const* d_in, const int* in_sizes, int n_in,
                              void* d_out, int out_size, void* d_ws, size_t ws_size,
                              hipStream_t stream) {
    const float* map3 = (const float*)d_in[0];
    const float* map4 = (const float*)d_in[1];
    const int*   tlbr = (const int*)d_in[2];
    const int*   p_imgh = (const int*)d_in[3];
    const int*   p_imgw = (const int*)d_in[4];
    float* out = (float*)d_out;

    const int C3 = 512, H3 = 128, C4 = 1024, H4 = 64;
    int B = in_sizes[0] / (C3 * H3 * H3);
    int N = in_sizes[2] / (B * 4);
    int ms = 2 + 4 * N + 6;
    const int MH3 = 24, MH4 = 16;

    char* wsp = (char*)d_ws;
    int* meta = (int*)wsp;
    size_t off = 4096;
    float* sim4 = (float*)(wsp + off);
    off += (size_t)B * N * 3 * H4 * H4 * 4;
    float* patches = (float*)(wsp + off);
    size_t pb3 = (size_t)B * N * C3 * MH3 * MH3 * 4;
    size_t pb4 = (size_t)B * N * C4 * MH4 * MH4 * 4;
    off += (pb3 > pb4 ? pb3 : pb4);
    unsigned short* Wbuf = (unsigned short*)(wsp + off);
    size_t wavail = (ws_size > off) ? (ws_size - off) : 0;
    size_t wpb3 = (size_t)16 * C3 * 24 * 24 * 2;   // 9.44 MB per batch
    size_t wpb4 = (size_t)16 * C4 * 16 * 16 * 2;   // 8.39 MB per batch
    int cb3 = (int)(wavail / wpb3); if (cb3 > B) cb3 = B; if (cb3 < 1) cb3 = 1;
    int cb4 = (int)(wavail / wpb4); if (cb4 > B) cb4 = B; if (cb4 < 1) cb4 = 1;

    k_meta<<<1, 1, 0, stream>>>(tlbr, p_imgh, p_imgw, B, N, ms, meta);

    { // ---- level 0 (m3) ----
        long long tot = (long long)B * N * C3 * MH3 * MH3;
        k_patches<<<(int)((tot + 255) / 256), 256, 0, stream>>>(
            map3, C3, H3, H3, patches, MH3, MH3, B, N, 0, ms, meta);
        for (int b0 = 0; b0 < B; b0 += cb3) {
            int cb = (cb3 < B - b0) ? cb3 : (B - b0);
            long long pr = (long long)cb * (C3 * 24 * 24 / 32) * 256;
            k_filters<512,24,24,24,24><<<(int)((pr + 255) / 256), 256, 0, stream>>>(
                patches, meta, Wbuf, b0, cb, N, 0, ms);
            dim3 grid(H3, cb);
            k_mfconv<512,24,24,128,128,4,2,152,40,12><<<grid, 256, 0, stream>>>(
                map3, Wbuf, out, b0, N, 6);
        }
    }
    { // ---- level 1 (m4) ----
        long long tot = (long long)B * N * C4 * MH4 * MH4;
        k_patches<<<(int)((tot + 255) / 256), 256, 0, stream>>>(
            map4, C4, H4, H4, patches, MH4, MH4, B, N, 1, ms, meta);
        for (int b0 = 0; b0 < B; b0 += cb4) {
            int cb = (cb4 < B - b0) ? cb4 : (B - b0);
            long long pr = (long long)cb * (C4 * 16 * 16 / 32) * 256;
            k_filters<1024,16,16,16,16><<<(int)((pr + 255) / 256), 256, 0, stream>>>(
                patches, meta, Wbuf, b0, cb, N, 1, ms);
            dim3 grid(H4, cb);
            k_mfconv<1024,16,16,64,64,8,1,80,24,8><<<grid, 256, 0, stream>>>(
                map4, Wbuf, sim4, b0, N, 3);
        }
        int tot2 = B * N * 3 * H3 * H3;
        k_upsample<<<(tot2 + 255) / 256, 256, 0, stream>>>(sim4, out, B, N);
    }
}